// Round 1
// baseline (37.087 us; speedup 1.0000x reference)
//
#include <hip/hip_runtime.h>

#define NN 2048

__global__ __launch_bounds__(256) void FlowEmbedder_kernel(
    const float* __restrict__ x,      // [N,2]
    const float* __restrict__ p,      // [3,2]
    float* __restrict__ out)          // [N,N]
{
    int idx = blockIdx.x * 256 + threadIdx.x;   // idx = i*N + j, exactly N*N threads
    int i = idx >> 11;                // / 2048
    int j = idx & (NN - 1);

    float2 xi = ((const float2*)x)[i];
    float2 xj = ((const float2*)x)[j];
    float dx = xj.x - xi.x;
    float dy = xj.y - xi.y;

    float dist = sqrtf(dx * dx + dy * dy);
    float invd = (dist > 0.0f) ? (1.0f / dist) : 0.0f;   // direction = 0 when dist==0
    float ux = dx * invd * 0.1f;      // step vector = STEP * unit(dir)
    float uy = dy * invd * 0.1f;

    // a_k = comb(3,k) * (p[k,0]*dx + p[k,1]*dy), comb = {1,3,3}
    float a0 =        p[0] * dx + p[1] * dy;
    float a1 = 3.0f * (p[2] * dx + p[3] * dy);
    float a2 = 3.0f * (p[4] * dx + p[5] * dy);

    // mask: t <= floor(dist / 0.1); IEEE divide to match numpy boundary behavior
    int tmax = (int)floorf(dist / 0.1f);
    tmax = (tmax > 15) ? 15 : tmax;

    float px = xi.x;
    float py = xi.y;
    float sum = 0.0f;
    for (int t = 0; t <= tmax; ++t) {
        // dot = a0*px^3 + a1*px^2*py + a2*px*py^2
        float dot = px * (px * (px * a0 + py * a1) + py * py * a2);
        sum += 1.0f + 4.0f * expf(-dot);
        px += ux;
        py += uy;
    }

    // cost = STEP * sum((1 + 4*exp(-dot))/5) = 0.02 * sum
    out[idx] = 0.02f * sum;
}

extern "C" void kernel_launch(void* const* d_in, const int* in_sizes, int n_in,
                              void* d_out, int out_size, void* d_ws, size_t ws_size,
                              hipStream_t stream) {
    const float* x = (const float*)d_in[0];   // embedded_points [2048,2]
    const float* p = (const float*)d_in[1];   // flow_field_parameters [3,2]
    float* out = (float*)d_out;               // [2048,2048]

    const int total = NN * NN;
    FlowEmbedder_kernel<<<total / 256, 256, 0, stream>>>(x, p, out);
}

// Round 2
// 28.176 us; speedup vs baseline: 1.3162x; 1.3162x over previous
//
#include <hip/hip_runtime.h>

#define NN 2048

__global__ __launch_bounds__(256) void FlowEmbedder_kernel(
    const float* __restrict__ x,      // [N,2]
    const float* __restrict__ p,      // [3,2]
    float* __restrict__ out)          // [N,N]
{
    int idx = blockIdx.x * 256 + threadIdx.x;   // idx = i*N + j, exactly N*N threads
    int i = idx >> 11;                // / 2048
    int j = idx & (NN - 1);

    float2 xi = ((const float2*)x)[i];
    float2 xj = ((const float2*)x)[j];
    float dx = xj.x - xi.x;
    float dy = xj.y - xi.y;

    float dist = sqrtf(dx * dx + dy * dy);
    float invd = (dist > 0.0f) ? (1.0f / dist) : 0.0f;   // direction = 0 when dist==0
    float ux = dx * invd * 0.1f;      // step vector = STEP * unit(dir)
    float uy = dy * invd * 0.1f;

    // a_k = comb(3,k) * (p[k,0]*dx + p[k,1]*dy), comb = {1,3,3}
    float a0 =        p[0] * dx + p[1] * dy;
    float a1 = 3.0f * (p[2] * dx + p[3] * dy);
    float a2 = 3.0f * (p[4] * dx + p[5] * dy);

    // mask: t <= floor(dist / 0.1); IEEE divide to match numpy boundary behavior
    int tmax = (int)floorf(dist / 0.1f);
    tmax = (tmax > 15) ? 15 : tmax;

    float px = xi.x;
    float py = xi.y;
    float sum_exp = 0.0f;
    #pragma unroll 4
    for (int t = 0; t <= tmax; ++t) {
        // dot = a0*px^3 + a1*px^2*py + a2*px*py^2
        float dot = px * (px * (px * a0 + py * a1) + py * py * a2);
        sum_exp += __expf(-dot);      // v_exp_f32 fast path
        px += ux;
        py += uy;
    }

    // cost = STEP * sum((1 + 4*exp(-dot))/5) = 0.02 * (count + 4*sum_exp)
    out[idx] = 0.02f * ((float)(tmax + 1) + 4.0f * sum_exp);
}

extern "C" void kernel_launch(void* const* d_in, const int* in_sizes, int n_in,
                              void* d_out, int out_size, void* d_ws, size_t ws_size,
                              hipStream_t stream) {
    const float* x = (const float*)d_in[0];   // embedded_points [2048,2]
    const float* p = (const float*)d_in[1];   // flow_field_parameters [3,2]
    float* out = (float*)d_out;               // [2048,2048]

    const int total = NN * NN;
    FlowEmbedder_kernel<<<total / 256, 256, 0, stream>>>(x, p, out);
}

// Round 3
// 25.954 us; speedup vs baseline: 1.4289x; 1.0856x over previous
//
#include <hip/hip_runtime.h>

#define NN 2048

__device__ __forceinline__ float cubic3(float px, float py, float b0, float b1, float b2) {
    // b0*px^3 + b1*px^2*py + b2*px*py^2 = px*(px*(px*b0 + py*b1) + py*py*b2)
    return px * (px * (px * b0 + py * b1) + (py * py) * b2);
}

__global__ __launch_bounds__(256) void FlowEmbedder_kernel(
    const float* __restrict__ x,      // [N,2]
    const float* __restrict__ p,      // [3,2]
    float* __restrict__ out)          // [N,N]
{
    int tid = blockIdx.x * 256 + threadIdx.x;   // 2 outputs per thread
    int i  = tid >> 10;                          // row (1024 threads per row)
    int j2 = tid & 1023;                         // pair-of-columns index

    float2 xi = ((const float2*)x)[i];
    float4 xj = ((const float4*)x)[j2];          // x[2*j2], x[2*j2+1]

    float p0 = p[0], p1 = p[1], p2 = p[2], p3 = p[3], p4 = p[4], p5 = p[5];

    const float NL  = -1.4426950408889634f;      // -log2(e)
    const float NL3 = -4.3280851226668903f;      // -3*log2(e)  (comb factor folded)

    // ---------- pair A ----------
    float dxA = xj.x - xi.x, dyA = xj.y - xi.y;
    float dA  = sqrtf(dxA * dxA + dyA * dyA);
    float ivA = (dA > 0.0f) ? (1.0f / dA) : 0.0f;
    float uxA = dxA * ivA * 0.1f, uyA = dyA * ivA * 0.1f;
    int   nA  = (int)floorf(dA / 0.1f); nA = nA > 15 ? 15 : nA;   // IEEE div: mask boundary fidelity
    float bA0 = NL  * (p0 * dxA + p1 * dyA);
    float bA1 = NL3 * (p2 * dxA + p3 * dyA);
    float bA2 = NL3 * (p4 * dxA + p5 * dyA);
    // exp2 argument d(t) = -log2(e)*dot(t) is cubic in t -> forward differences
    float f0A = cubic3(xi.x,            xi.y,            bA0, bA1, bA2);
    float f1A = cubic3(xi.x + uxA,      xi.y + uyA,      bA0, bA1, bA2);
    float f2A = cubic3(xi.x + 2.f*uxA,  xi.y + 2.f*uyA,  bA0, bA1, bA2);
    float c3A = cubic3(uxA, uyA, bA0, bA1, bA2);
    float dvA = f0A;
    float d1A = f1A - f0A;
    float d2A = f2A - 2.0f * f1A + f0A;
    float d3A = 6.0f * c3A;

    // ---------- pair B ----------
    float dxB = xj.z - xi.x, dyB = xj.w - xi.y;
    float dB  = sqrtf(dxB * dxB + dyB * dyB);
    float ivB = (dB > 0.0f) ? (1.0f / dB) : 0.0f;
    float uxB = dxB * ivB * 0.1f, uyB = dyB * ivB * 0.1f;
    int   nB  = (int)floorf(dB / 0.1f); nB = nB > 15 ? 15 : nB;
    float bB0 = NL  * (p0 * dxB + p1 * dyB);
    float bB1 = NL3 * (p2 * dxB + p3 * dyB);
    float bB2 = NL3 * (p4 * dxB + p5 * dyB);
    float f0B = cubic3(xi.x,            xi.y,            bB0, bB1, bB2);
    float f1B = cubic3(xi.x + uxB,      xi.y + uyB,      bB0, bB1, bB2);
    float f2B = cubic3(xi.x + 2.f*uxB,  xi.y + 2.f*uyB,  bB0, bB1, bB2);
    float c3B = cubic3(uxB, uyB, bB0, bB1, bB2);
    float dvB = f0B;
    float d1B = f1B - f0B;
    float d2B = f2B - 2.0f * f1B + f0B;
    float d3B = 6.0f * c3B;

    int maxT = nA > nB ? nA : nB;
    float sA = 0.0f, sB = 0.0f;
    #pragma unroll 4
    for (int t = 0; t <= maxT; ++t) {
        float eA = __builtin_amdgcn_exp2f(dvA);   // = exp(-dot_A(t))
        float eB = __builtin_amdgcn_exp2f(dvB);
        if (t <= nA) sA += eA;                    // cndmask accumulate
        if (t <= nB) sB += eB;
        dvA += d1A; d1A += d2A; d2A += d3A;
        dvB += d1B; d1B += d2B; d2B += d3B;
    }

    // cost = 0.1 * sum((1 + 4*exp(-dot))/5) = 0.02*(count + 4*sum_exp)
    float cA = 0.02f * ((float)(nA + 1) + 4.0f * sA);
    float cB = 0.02f * ((float)(nB + 1) + 4.0f * sB);
    ((float2*)out)[tid] = make_float2(cA, cB);    // out index 2*tid, 2*tid+1
}

extern "C" void kernel_launch(void* const* d_in, const int* in_sizes, int n_in,
                              void* d_out, int out_size, void* d_ws, size_t ws_size,
                              hipStream_t stream) {
    const float* x = (const float*)d_in[0];   // embedded_points [2048,2]
    const float* p = (const float*)d_in[1];   // flow_field_parameters [3,2]
    float* out = (float*)d_out;               // [2048,2048]

    const int total_threads = NN * NN / 2;    // 2 outputs per thread
    FlowEmbedder_kernel<<<total_threads / 256, 256, 0, stream>>>(x, p, out);
}